// Round 2
// baseline (538.491 us; speedup 1.0000x reference)
//
#include <hip/hip_runtime.h>

// Match numpy f32 semantics exactly: no FMA contraction anywhere in this file.
#pragma clang fp contract(off)

#define NBOX   1024
#define NCLS   32
#define NBATCH 8
#define MAXOUT 300

// a = suppressor (earlier in sorted order), b = candidate. Boxes are
// (y1,x1,y2,x2) in (x,y,z,w). Mirrors the reference op order exactly:
// inter = max(yy2-yy1,0)*max(xx2-xx1,0); iou = inter/((area_i+area_j)-inter)
__device__ __forceinline__ bool sup_f(float4 a, float4 b) {
#pragma clang fp contract(off)
  float areaA = (a.z - a.x) * (a.w - a.y);
  float areaB = (b.z - b.x) * (b.w - b.y);
  float yy1 = fmaxf(a.x, b.x);
  float xx1 = fmaxf(a.y, b.y);
  float yy2 = fminf(a.z, b.z);
  float xx2 = fminf(a.w, b.w);
  float ih = fmaxf(yy2 - yy1, 0.0f);
  float iw = fmaxf(xx2 - xx1, 0.0f);
  float inter = ih * iw;
  float denom = (areaA + areaB) - inter;
  float iou = inter / denom;
  return iou > 0.5f;
}

// One wave (64 threads) per (batch, class) pair. Sort 1024 (score,idx) keys
// descending in LDS, then greedy NMS in exact sorted order, emit <=300 kept
// records (uint64 global-order keys) to workspace.
__global__ __launch_bounds__(64) void nms_per_class(
    const float* __restrict__ boxes, const float* __restrict__ scores,
    unsigned long long* __restrict__ recs, int* __restrict__ cnts) {
  const int bc = blockIdx.x;
  const int b = bc >> 5;       // /NCLS
  const int c = bc & (NCLS - 1);
  const int lane = threadIdx.x;

  __shared__ unsigned long long key[NBOX];
  __shared__ float4 sbox[NBOX];
  __shared__ float4 kbox[NBOX];

  // Build keys: score_bits<<32 | (1023-n). Descending sort => score desc,
  // ties by original index ascending (stable). Invalid (s<=0.5) => high32=0.
  const float* sp = scores + (size_t)b * NBOX * NCLS + c;
  for (int p0 = 0; p0 < NBOX; p0 += 64) {
    int n = p0 + lane;
    float s = sp[(size_t)n * NCLS];
    unsigned sb = __float_as_uint(s);
    unsigned long long k = (s > 0.5f)
        ? ((((unsigned long long)sb) << 32) | (unsigned)(NBOX - 1 - n))
        : (unsigned long long)(unsigned)(NBOX - 1 - n);
    key[n] = k;
  }
  __syncthreads();

  // Bitonic sort, descending, 1024 elements, one wave.
  for (unsigned kk = 2; kk <= NBOX; kk <<= 1) {
    for (unsigned jj = kk >> 1; jj > 0; jj >>= 1) {
      for (unsigned i = (unsigned)lane; i < NBOX; i += 64) {
        unsigned ixj = i ^ jj;
        if (ixj > i) {
          unsigned long long a = key[i], bb = key[ixj];
          bool up = ((i & kk) == 0);
          bool sw = up ? (a < bb) : (a > bb);
          if (sw) { key[i] = bb; key[ixj] = a; }
        }
      }
      __syncthreads();
    }
  }

  // Gather boxes in sorted order; count valid V (valid entries are a prefix).
  const float4* gb = (const float4*)boxes + (size_t)b * NBOX;
  int V = 0;
  for (int p0 = 0; p0 < NBOX; p0 += 64) {
    int p = p0 + lane;
    unsigned long long k = key[p];
    bool valid = (k >> 32) != 0ull;
    int n = NBOX - 1 - (int)(k & (NBOX - 1));
    sbox[p] = gb[n];
    V += (int)__popcll(__ballot(valid));
  }
  __syncthreads();

  // Greedy NMS: tiles of 64. Phase A: suppress vs previously kept boxes.
  // Phase B: sequential intra-tile (exact greedy order).
  int Kc = 0;
  const int base = bc * MAXOUT;
  const int nT = (V + 63) >> 6;
  for (int t = 0; t < nT; ++t) {
    int p = (t << 6) + lane;          // p <= 1023 always
    bool alive = (p < V);
    float4 mb = sbox[p];
    for (int k2 = 0; k2 < Kc; ++k2) {
      float4 kb = kbox[k2];           // broadcast read
      if (alive && sup_f(kb, mb)) alive = false;
    }
    for (int i = 0; i < 64; ++i) {
      unsigned long long mask = __ballot(alive);
      if ((mask >> i) & 1ull) {       // wave-uniform branch
        float4 bi;
        bi.x = __shfl(mb.x, i);
        bi.y = __shfl(mb.y, i);
        bi.z = __shfl(mb.z, i);
        bi.w = __shfl(mb.w, i);
        if (lane > i && alive && sup_f(bi, mb)) alive = false;
      }
    }
    unsigned long long mask = __ballot(alive);
    int rank = Kc + (int)__popcll(mask & ((1ull << lane) - 1ull));
    if (alive) {
      kbox[rank] = mb;
      if (rank < MAXOUT) {
        unsigned long long k = key[p];
        unsigned sb = (unsigned)(k >> 32);
        int n = NBOX - 1 - (int)(k & (NBOX - 1));
        int flat = c * NBOX + p;      // class-major flatten index
        unsigned long long rec = (((unsigned long long)sb) << 32)
            | ((unsigned)(NCLS * NBOX - 1 - flat) << 10) | (unsigned)n;
        recs[base + rank] = rec;
      }
    }
    Kc += (int)__popcll(mask);
    __syncthreads();
  }
  if (lane == 0) cnts[bc] = (Kc < MAXOUT) ? Kc : MAXOUT;
}

// One 1024-thread block per batch. Exact top-300 by key via binary search on
// the (unique) key space; dedup by box id via LDS atomicMax (key order ==
// top-300 position order); prefix scan for ascending-box-id output slots.
__global__ __launch_bounds__(1024) void topk_out(
    const float* __restrict__ boxes,
    const unsigned long long* __restrict__ recs,
    const int* __restrict__ cnts,
    float* __restrict__ out) {
  const int b = blockIdx.x;
  const int tid = threadIdx.x;

  __shared__ unsigned long long maxKey[NBOX];
  __shared__ int sc[NBOX];
  __shared__ int redCnt;

  // Load candidates (<= 32*300 = 9600) into registers, 10 per thread.
  const int CAND = NCLS * MAXOUT;
  unsigned long long cand[10];
#pragma unroll
  for (int q = 0; q < 10; ++q) {
    int j = tid + (q << 10);
    unsigned long long v = 0;
    if (j < CAND) {
      int c = j / MAXOUT;
      int r = j - c * MAXOUT;
      if (r < cnts[b * NCLS + c])
        v = recs[(size_t)(b * NCLS + c) * MAXOUT + r];
    }
    cand[q] = v;
  }

  maxKey[tid] = 0;
  __syncthreads();

  // Binary search for the 300th-largest key T (keys unique). If fewer than
  // 300 candidates exist, converges to T=0 (then select all nonzero).
  unsigned long long lo = 0, hi = (~0ull) >> 1;
  while (lo < hi) {
    unsigned long long mid = lo + ((hi - lo + 1) >> 1);
    if (tid == 0) redCnt = 0;
    __syncthreads();
    int local = 0;
#pragma unroll
    for (int q = 0; q < 10; ++q) local += (cand[q] >= mid) ? 1 : 0;
    for (int off = 32; off > 0; off >>= 1) local += __shfl_down(local, off);
    if ((tid & 63) == 0) atomicAdd(&redCnt, local);
    __syncthreads();
    int tot = redCnt;
    __syncthreads();
    if (tot >= MAXOUT) lo = mid; else hi = mid - 1;
  }
  const unsigned long long T = lo;

  // Dedup: per box id keep the max key (== earliest top-300 occurrence).
#pragma unroll
  for (int q = 0; q < 10; ++q) {
    unsigned long long v = cand[q];
    if (v != 0ull && v >= T) {
      int n = (int)(v & (NBOX - 1));
      atomicMax(&maxKey[n], v);
    }
  }
  __syncthreads();

  // Present flags + inclusive prefix scan over 1024 box ids.
  int pres = (maxKey[tid] != 0ull) ? 1 : 0;
  sc[tid] = pres;
  __syncthreads();
  for (int off = 1; off < NBOX; off <<= 1) {
    int v = (tid >= off) ? sc[tid - off] : 0;
    __syncthreads();
    if (tid >= off) sc[tid] += v;
    __syncthreads();
  }
  int total = sc[NBOX - 1];

  float* ob = out + (size_t)b * MAXOUT * 4;
  float* os = out + (size_t)NBATCH * MAXOUT * 4 + (size_t)b * MAXOUT;
  float* oc = out + (size_t)NBATCH * MAXOUT * 5 + (size_t)b * MAXOUT;

  if (pres) {
    int slot = sc[tid] - 1;
    unsigned long long v = maxKey[tid];
    float score = __uint_as_float((unsigned)(v >> 32));
    int flat = NCLS * NBOX - 1 - (int)((v >> 10) & (unsigned)(NCLS * NBOX - 1));
    int cls = flat >> 10;
    float4 bx = ((const float4*)boxes)[(size_t)b * NBOX + tid];
    ob[slot * 4 + 0] = bx.x;
    ob[slot * 4 + 1] = bx.y;
    ob[slot * 4 + 2] = bx.z;
    ob[slot * 4 + 3] = bx.w;
    os[slot] = score;
    oc[slot] = (float)cls;
  }
  if (tid >= total && tid < MAXOUT) {
    ob[tid * 4 + 0] = 0.0f; ob[tid * 4 + 1] = 0.0f;
    ob[tid * 4 + 2] = 0.0f; ob[tid * 4 + 3] = 0.0f;
    os[tid] = 0.0f;
    oc[tid] = 0.0f;
  }
}

extern "C" void kernel_launch(void* const* d_in, const int* in_sizes, int n_in,
                              void* d_out, int out_size, void* d_ws, size_t ws_size,
                              hipStream_t stream) {
  const float* boxes  = (const float*)d_in[0];   // [8,1024,4] f32
  const float* scores = (const float*)d_in[1];   // [8,1024,32] f32
  float* out = (float*)d_out;                    // boxes ‖ scores ‖ classes (f32)

  unsigned long long* recs = (unsigned long long*)d_ws;  // 256*300 u64
  int* cnts = (int*)((char*)d_ws + (size_t)NBATCH * NCLS * MAXOUT * sizeof(unsigned long long));

  nms_per_class<<<NBATCH * NCLS, 64, 0, stream>>>(boxes, scores, recs, cnts);
  topk_out<<<NBATCH, 1024, 0, stream>>>(boxes, recs, cnts, out);
}

// Round 3
// 170.226 us; speedup vs baseline: 3.1634x; 3.1634x over previous
//
#include <hip/hip_runtime.h>

// Match numpy f32 semantics exactly: no FMA contraction anywhere in this file.
#pragma clang fp contract(off)

#define NBOX   1024
#define NCLS   32
#define NBATCH 8
#define MAXOUT 300

// IoU > 0.5 test, byte-identical op order to the reference (verified absmax
// 0.0 in round 2). Keep the true f32 division — it is the exactness anchor.
__device__ __forceinline__ bool sup_f(float4 a, float4 b) {
#pragma clang fp contract(off)
  float areaA = (a.z - a.x) * (a.w - a.y);
  float areaB = (b.z - b.x) * (b.w - b.y);
  float yy1 = fmaxf(a.x, b.x);
  float xx1 = fmaxf(a.y, b.y);
  float yy2 = fminf(a.z, b.z);
  float xx2 = fminf(a.w, b.w);
  float ih = fmaxf(yy2 - yy1, 0.0f);
  float iw = fmaxf(xx2 - xx1, 0.0f);
  float inter = ih * iw;
  float denom = (areaA + areaB) - inter;
  float iou = inter / denom;
  return iou > 0.5f;
}

// One 512-thread block (8 waves) per (batch, class): bitonic sort 1024 keys,
// parallel pairwise suppressor-bitmask build (thread t owns sorted positions
// t and t+512), then bit-parallel Jacobi fixpoint == exact greedy NMS.
__global__ __launch_bounds__(512) void nms_per_class(
    const float* __restrict__ boxes, const float* __restrict__ scores,
    unsigned long long* __restrict__ recs, int* __restrict__ cnts) {
  const int bc = blockIdx.x;
  const int b = bc >> 5;
  const int c = bc & (NCLS - 1);
  const int t = threadIdx.x;        // 0..511
  const int wav = t >> 6, lane = t & 63;

  __shared__ unsigned long long key[NBOX];
  __shared__ float4 sbox[NBOX];
  __shared__ unsigned long long keepw[16];
  __shared__ int shV;
  __shared__ int shChanged;

  // Keys: score_bits<<32 | (1023-n); invalid => high32==0. Descending sort
  // => score desc, ties by original index asc (matches stable argsort).
  const float* sp = scores + (size_t)b * NBOX * NCLS + c;
  for (int q = 0; q < 2; ++q) {
    int n = t + (q << 9);
    float s = sp[(size_t)n * NCLS];
    unsigned sb = __float_as_uint(s);
    key[n] = (s > 0.5f)
        ? ((((unsigned long long)sb) << 32) | (unsigned)(NBOX - 1 - n))
        : (unsigned long long)(unsigned)(NBOX - 1 - n);
  }
  if (t == 0) shV = 0;
  __syncthreads();

  // Bitonic sort, descending, 512 threads x 1 pair per stage.
  for (unsigned kk = 2; kk <= NBOX; kk <<= 1) {
    for (unsigned jj = kk >> 1; jj > 0; jj >>= 1) {
      unsigned i = (((unsigned)t & ~(jj - 1)) << 1) | ((unsigned)t & (jj - 1));
      unsigned ixj = i | jj;
      unsigned long long a = key[i], bb = key[ixj];
      bool up = ((i & kk) == 0);
      if (up ? (a < bb) : (a > bb)) { key[i] = bb; key[ixj] = a; }
      __syncthreads();
    }
  }

  // V = #valid (valid entries are the sorted prefix); gather boxes.
  int lv = 0;
  const float4* gb = (const float4*)boxes + (size_t)b * NBOX;
  for (int q = 0; q < 2; ++q) {
    int p = t + (q << 9);
    unsigned long long k = key[p];
    lv += ((k >> 32) != 0ull) ? 1 : 0;
    int n = NBOX - 1 - (int)(k & (NBOX - 1));
    sbox[p] = gb[n];
  }
  for (int off = 32; off > 0; off >>= 1) lv += __shfl_down(lv, off);
  if (lane == 0) atomicAdd(&shV, lv);
  __syncthreads();
  const int V = shV;

  // keep init = valid prefix.
  if (t < 16) {
    int base = t * 64;
    unsigned long long m;
    if (V >= base + 64) m = ~0ull;
    else if (V <= base) m = 0ull;
    else m = (1ull << (V - base)) - 1ull;
    keepw[t] = m;
  }
  __syncthreads();

  // Pairwise suppressor bitmasks. j1 = t (<512), j2 = t+512.
  const int j1 = t, j2 = t + 512;
  const bool a1 = j1 < V, a2 = j2 < V;
  float4 bj1 = sbox[j1];
  float4 bj2 = sbox[j2];
  int bound = min(V, 64 * (wav + 1));
  if (V > 512 + 64 * wav) bound = V;   // wave has live j2 work

  unsigned long long m1[8];
  unsigned long long m2[16];
#pragma unroll
  for (int w = 0; w < 16; ++w) {
    unsigned long long acc1 = 0, acc2 = 0;
    int i0 = w << 6;
    int ie = min(bound, i0 + 64);
    for (int i = i0; i < ie; ++i) {
      float4 bi = sbox[i];   // wave-uniform broadcast read
      unsigned long long bit = 1ull << (i & 63);
      if (w < 8) {
        if (a1 && i < j1 && sup_f(bi, bj1)) acc1 |= bit;
      }
      if (a2 && i < j2 && sup_f(bi, bj2)) acc2 |= bit;
    }
    if (w < 8) m1[w] = acc1;
    m2[w] = acc2;
  }

  // Jacobi fixpoint: keep[j] = (j<V) && !any kept suppressor. Unique fixpoint
  // == greedy NMS; converges in <= chain depth iterations.
  for (int it = 0; it < 1100; ++it) {
    bool s1 = false, s2 = false;
#pragma unroll
    for (int w = 0; w < 8; ++w) s1 |= (m1[w] & keepw[w]) != 0ull;
#pragma unroll
    for (int w = 0; w < 16; ++w) s2 |= (m2[w] & keepw[w]) != 0ull;
    unsigned long long w1 = __ballot(a1 && !s1);
    unsigned long long w2 = __ballot(a2 && !s2);
    unsigned long long o1 = keepw[wav], o2 = keepw[8 + wav];
    __syncthreads();
    if (t == 0) shChanged = 0;
    if (lane == 0) { keepw[wav] = w1; keepw[8 + wav] = w2; }
    __syncthreads();
    if (lane == 0 && (w1 != o1 || w2 != o2)) atomicOr(&shChanged, 1);
    __syncthreads();
    if (!shChanged) break;
  }

  // Emit kept records (class rank < 300) + count.
  if (t == 0) {
    int tot = 0;
#pragma unroll
    for (int w = 0; w < 16; ++w) tot += (int)__popcll(keepw[w]);
    cnts[bc] = (tot < MAXOUT) ? tot : MAXOUT;
  }
  const int base = bc * MAXOUT;
  if (a1 && ((keepw[wav] >> lane) & 1ull)) {
    int rank = 0;
    for (int w = 0; w < wav; ++w) rank += (int)__popcll(keepw[w]);
    rank += (int)__popcll(keepw[wav] & ((1ull << lane) - 1ull));
    if (rank < MAXOUT) {
      unsigned long long k = key[j1];
      unsigned sb = (unsigned)(k >> 32);
      int n = NBOX - 1 - (int)(k & (NBOX - 1));
      int flat = c * NBOX + j1;
      recs[base + rank] = (((unsigned long long)sb) << 32)
          | ((unsigned)(NCLS * NBOX - 1 - flat) << 10) | (unsigned)n;
    }
  }
  if (a2 && ((keepw[8 + wav] >> lane) & 1ull)) {
    int rank = 0;
    for (int w = 0; w < 8 + wav; ++w) rank += (int)__popcll(keepw[w]);
    rank += (int)__popcll(keepw[8 + wav] & ((1ull << lane) - 1ull));
    if (rank < MAXOUT) {
      unsigned long long k = key[j2];
      unsigned sb = (unsigned)(k >> 32);
      int n = NBOX - 1 - (int)(k & (NBOX - 1));
      int flat = c * NBOX + j2;
      recs[base + rank] = (((unsigned long long)sb) << 32)
          | ((unsigned)(NCLS * NBOX - 1 - flat) << 10) | (unsigned)n;
    }
  }
}

// One 1024-thread block per batch. Exact top-300 via 256-bucket score
// histogram + suffix scan + exact rank inside the boundary bucket (keys are
// unique). Then LDS atomicMax dedup by box id and ballot-based slot scan.
__global__ __launch_bounds__(1024) void topk_out(
    const float* __restrict__ boxes,
    const unsigned long long* __restrict__ recs,
    const int* __restrict__ cnts,
    float* __restrict__ out) {
  const int b = blockIdx.x;
  const int tid = threadIdx.x;
  const int lane = tid & 63, wav = tid >> 6;

  __shared__ int hist[256];
  __shared__ int suf[257];
  __shared__ unsigned long long maxKey[NBOX];
  __shared__ unsigned long long blist[1024];
  __shared__ int bcnt;
  __shared__ unsigned long long shT;
  __shared__ int shBstar;
  __shared__ int wcnt[16], woff[16];
  __shared__ int shPresTot;

  const int CAND = NCLS * MAXOUT;
  unsigned long long cand[10];
#pragma unroll
  for (int q = 0; q < 10; ++q) {
    int j = tid + (q << 10);
    unsigned long long v = 0;
    if (j < CAND) {
      int c = j / MAXOUT;
      int r = j - c * MAXOUT;
      if (r < cnts[b * NCLS + c])
        v = recs[(size_t)(b * NCLS + c) * MAXOUT + r];
    }
    cand[q] = v;
  }
  maxKey[tid] = 0;
  if (tid < 256) hist[tid] = 0;
  if (tid == 0) { bcnt = 0; shT = 0; shBstar = -1; }
  __syncthreads();

  // Histogram on score-bit buckets; score in (0.5,1) => bits in
  // (0x3F000000, 0x3F800000) => bucket = (bits - 0x3F000000) >> 15 in [0,255].
#pragma unroll
  for (int q = 0; q < 10; ++q) {
    unsigned long long v = cand[q];
    if (v != 0ull) {
      int bk = (int)(((unsigned)(v >> 32) - 0x3F000000u) >> 15);
      atomicAdd(&hist[bk], 1);
    }
  }
  __syncthreads();

  // Wave 0: suffix sums over the 256 buckets.
  if (wav == 0) {
    int h[4];
#pragma unroll
    for (int g = 0; g < 4; ++g) h[g] = hist[g * 64 + lane];
#pragma unroll
    for (int g = 0; g < 4; ++g) {
      int v = h[g];
#pragma unroll
      for (int off = 1; off < 64; off <<= 1) {
        int u = __shfl_down(v, off);
        if (lane + off < 64) v += u;
      }
      h[g] = v;                       // suffix within group
    }
    int sum1 = __shfl(h[1], 0);
    int sum2 = __shfl(h[2], 0);
    int sum3 = __shfl(h[3], 0);
    suf[0 * 64 + lane] = h[0] + sum1 + sum2 + sum3;
    suf[1 * 64 + lane] = h[1] + sum2 + sum3;
    suf[2 * 64 + lane] = h[2] + sum3;
    suf[3 * 64 + lane] = h[3];
    if (lane == 0) suf[256] = 0;
  }
  __syncthreads();

  // Boundary bucket B*: suf[B*] >= 300 > suf[B*+1]. (-1 if total < 300.)
  if (tid < 256) {
    if (suf[tid] >= MAXOUT && suf[tid + 1] < MAXOUT) shBstar = tid;
  }
  __syncthreads();
  const int Bstar = shBstar;

  if (Bstar >= 0) {   // block-uniform branch
#pragma unroll
    for (int q = 0; q < 10; ++q) {
      unsigned long long v = cand[q];
      if (v != 0ull) {
        int bk = (int)(((unsigned)(v >> 32) - 0x3F000000u) >> 15);
        if (bk == Bstar) { int idx = atomicAdd(&bcnt, 1); blist[idx] = v; }
      }
    }
    __syncthreads();
    int M = bcnt;
    int need = MAXOUT - suf[Bstar + 1];
    if (tid < M) {
      unsigned long long mine = blist[tid];
      int r = 0;
      for (int i = 0; i < M; ++i) r += (blist[i] > mine) ? 1 : 0;
      if (r == need - 1) shT = mine;   // the 300th-largest key overall
    }
    __syncthreads();
  }
  const unsigned long long T = shT;   // 0 => select all nonzero

  // Dedup by original box id: max key == earliest top-300 occurrence.
#pragma unroll
  for (int q = 0; q < 10; ++q) {
    unsigned long long v = cand[q];
    if (v != 0ull && v >= T) {
      int n = (int)(v & (NBOX - 1));
      atomicMax(&maxKey[n], v);
    }
  }
  __syncthreads();

  // Present flags -> output slot via ballot scan (box ids ascending).
  bool pres = (maxKey[tid] != 0ull);
  unsigned long long wm = __ballot(pres);
  if (lane == 0) wcnt[wav] = (int)__popcll(wm);
  __syncthreads();
  if (tid < 16) {
    int v = wcnt[tid];
    int inc = v;
#pragma unroll
    for (int off = 1; off < 16; off <<= 1) {
      int u = __shfl_up(inc, off);
      if (lane >= off) inc += u;
    }
    woff[tid] = inc - v;
    if (tid == 15) shPresTot = inc;
  }
  __syncthreads();
  const int total = shPresTot;

  float* ob = out + (size_t)b * MAXOUT * 4;
  float* os = out + (size_t)NBATCH * MAXOUT * 4 + (size_t)b * MAXOUT;
  float* oc = out + (size_t)NBATCH * MAXOUT * 5 + (size_t)b * MAXOUT;

  if (pres) {
    int slot = woff[wav] + (int)__popcll(wm & ((1ull << lane) - 1ull));
    unsigned long long v = maxKey[tid];
    float score = __uint_as_float((unsigned)(v >> 32));
    int flat = NCLS * NBOX - 1 - (int)((v >> 10) & (unsigned)(NCLS * NBOX - 1));
    int cls = flat >> 10;
    float4 bx = ((const float4*)boxes)[(size_t)b * NBOX + tid];
    ob[slot * 4 + 0] = bx.x;
    ob[slot * 4 + 1] = bx.y;
    ob[slot * 4 + 2] = bx.z;
    ob[slot * 4 + 3] = bx.w;
    os[slot] = score;
    oc[slot] = (float)cls;
  }
  if (tid >= total && tid < MAXOUT) {
    ob[tid * 4 + 0] = 0.0f; ob[tid * 4 + 1] = 0.0f;
    ob[tid * 4 + 2] = 0.0f; ob[tid * 4 + 3] = 0.0f;
    os[tid] = 0.0f;
    oc[tid] = 0.0f;
  }
}

extern "C" void kernel_launch(void* const* d_in, const int* in_sizes, int n_in,
                              void* d_out, int out_size, void* d_ws, size_t ws_size,
                              hipStream_t stream) {
  const float* boxes  = (const float*)d_in[0];   // [8,1024,4] f32
  const float* scores = (const float*)d_in[1];   // [8,1024,32] f32
  float* out = (float*)d_out;                    // boxes ‖ scores ‖ classes (f32)

  unsigned long long* recs = (unsigned long long*)d_ws;  // 256*300 u64
  int* cnts = (int*)((char*)d_ws + (size_t)NBATCH * NCLS * MAXOUT * sizeof(unsigned long long));

  nms_per_class<<<NBATCH * NCLS, 512, 0, stream>>>(boxes, scores, recs, cnts);
  topk_out<<<NBATCH, 1024, 0, stream>>>(boxes, recs, cnts, out);
}

// Round 4
// 125.472 us; speedup vs baseline: 4.2917x; 1.3567x over previous
//
#include <hip/hip_runtime.h>

// Match numpy f32 semantics exactly: no FMA contraction anywhere in this file.
#pragma clang fp contract(off)

#define NBOX   1024
#define NCLS   32
#define NBATCH 8
#define MAXOUT 300
#define SMAX   11   // fast path handles V <= 704 (Binom(1024,.5) mean 512, sd 16)

// 64-bit shfl_xor built from two 32-bit shfls (deterministic, wave64).
__device__ __forceinline__ unsigned long long shflx64(unsigned long long v, int m) {
  unsigned lo = (unsigned)__shfl_xor((int)(unsigned)v, m, 64);
  unsigned hi = (unsigned)__shfl_xor((int)(unsigned)(v >> 32), m, 64);
  return ((unsigned long long)hi << 32) | lo;
}

// Bitonic compare-exchange in registers; final order descending. Keys unique.
__device__ __forceinline__ unsigned long long cexch(
    unsigned long long mine, int jj, int kk, int t) {
  unsigned long long other = shflx64(mine, jj);
  bool iLow = ((t & jj) == 0);
  bool desc = ((t & kk) == 0);
  bool wantMax = (iLow == desc);
  bool otherBigger = (other > mine);
  return (wantMax == otherBigger) ? other : mine;
}

// One 1024-thread block per (batch,class). Thread t owns sorted position t.
__global__ __launch_bounds__(1024) void nms_per_class(
    const float* __restrict__ boxes, const float* __restrict__ scores,
    unsigned long long* __restrict__ recs, int* __restrict__ cnts) {
#pragma clang fp contract(off)
  const int bc = blockIdx.x;
  const int b = bc >> 5;
  const int c = bc & (NCLS - 1);
  const int t = threadIdx.x;
  const int lane = t & 63, wav = t >> 6;

  __shared__ unsigned long long key[NBOX];
  __shared__ float4 sbox[NBOX];
  __shared__ float sarea[NBOX];
  __shared__ unsigned long long mask[64 * 66];   // triangular-packed, S<=11
  __shared__ unsigned long long keepw[16];
  __shared__ int shV, shChanged;

  // Key: score_bits<<32 | (1023-n); invalid => high32==0. Descending order
  // == score desc, ties by original index asc (stable argsort semantics).
  const float* sp = scores + (size_t)b * NBOX * NCLS + c;
  float s = sp[(size_t)t * NCLS];
  bool valid = (s > 0.5f);
  unsigned long long mine = valid
      ? ((((unsigned long long)__float_as_uint(s)) << 32) | (unsigned)(NBOX - 1 - t))
      : (unsigned long long)(unsigned)(NBOX - 1 - t);
  if (t == 0) shV = 0;
  __syncthreads();
  unsigned long long vb = __ballot(valid);
  if (lane == 0) atomicAdd(&shV, (int)__popcll(vb));

  // Bitonic sort, descending. Stages with jj<=32 run in registers (no
  // barrier); only jj>=64 stages touch LDS. 10 LDS stages vs 55 before.
  for (int kk = 2; kk <= 64; kk <<= 1)
    for (int jj = kk >> 1; jj > 0; jj >>= 1)
      mine = cexch(mine, jj, kk, t);
  key[t] = mine;
  __syncthreads();
  for (int kk = 128; kk <= 1024; kk <<= 1) {
    for (int jj = kk >> 1; jj >= 64; jj >>= 1) {
      if (t < 512) {
        int i = ((t & ~(jj - 1)) << 1) | (t & (jj - 1));
        int ixj = i | jj;
        unsigned long long a = key[i], bb = key[ixj];
        if (((i & kk) == 0) ? (a < bb) : (a > bb)) { key[i] = bb; key[ixj] = a; }
      }
      __syncthreads();
    }
    mine = key[t];
    for (int jj = 32; jj > 0; jj >>= 1) mine = cexch(mine, jj, kk, t);
    key[t] = mine;
    __syncthreads();
  }

  // Gather boxes in sorted order; precompute areas (same expression as ref).
  int n0 = NBOX - 1 - (int)(mine & (NBOX - 1));
  const float4* gb = (const float4*)boxes + (size_t)b * NBOX;
  float4 bx4 = gb[n0];
  sbox[t] = bx4;
  sarea[t] = (bx4.z - bx4.x) * (bx4.w - bx4.y);
  __syncthreads();
  const int V = shV;
  const int S = (V + 63) >> 6;
  const bool aj = (t < V);

  // keep init = valid prefix.
  if (t < 16) {
    int base = t * 64;
    unsigned long long m0;
    if (V >= base + 64) m0 = ~0ull;
    else if (V <= base) m0 = 0ull;
    else m0 = (1ull << (V - base)) - 1ull;
    keepw[t] = m0;
  }

  unsigned long long m[16];
#pragma unroll
  for (int w = 0; w < 16; ++w) m[w] = 0;

  if (S <= SMAX) {
    // Strip-pair worklist: unit (J,I), I<=J, round-robin over 16 waves.
    // i-boxes live in lane regs, broadcast via v_readlane: zero LDS traffic
    // in the 64-step loop -> VALU-bound, fully unrolled.
    const int T = S * (S + 1) / 2;
    for (int k = wav; k < T; k += 16) {
      int J = 0;
      while ((J + 1) * (J + 2) / 2 <= k) ++J;   // wave-uniform, <=11 iters
      int I = k - J * (J + 1) / 2;
      int j = (J << 6) + lane;
      float4 bj = sbox[j];
      float areaj = sarea[j];
      float4 bi = sbox[(I << 6) + lane];
      float areai = sarea[(I << 6) + lane];
      bool actj = (j < V);
      unsigned long long acc = 0;
#pragma unroll
      for (int q = 0; q < 64; ++q) {
        float ax = __uint_as_float((unsigned)__builtin_amdgcn_readlane((int)__float_as_uint(bi.x), q));
        float ay = __uint_as_float((unsigned)__builtin_amdgcn_readlane((int)__float_as_uint(bi.y), q));
        float az = __uint_as_float((unsigned)__builtin_amdgcn_readlane((int)__float_as_uint(bi.z), q));
        float aw = __uint_as_float((unsigned)__builtin_amdgcn_readlane((int)__float_as_uint(bi.w), q));
        float aa = __uint_as_float((unsigned)__builtin_amdgcn_readlane((int)__float_as_uint(areai), q));
        // suppressor = i (ax..aw, area aa), candidate = j. Byte-identical
        // op order to the reference (verified absmax 0.0).
        float yy1 = fmaxf(ax, bj.x);
        float xx1 = fmaxf(ay, bj.y);
        float yy2 = fminf(az, bj.z);
        float xx2 = fminf(aw, bj.w);
        float ih = fmaxf(yy2 - yy1, 0.0f);
        float iw = fmaxf(xx2 - xx1, 0.0f);
        float inter = ih * iw;
        float denom = (aa + areaj) - inter;
        float iou = inter / denom;
        bool pred = actj && (I < J || q < lane) && (iou > 0.5f);
        if (pred) acc |= (1ull << q);
      }
      mask[((J * (J + 1) / 2) << 6) + lane * (J + 1) + I] = acc;
    }
    __syncthreads();
    if (t < (S << 6)) {
      int J = t >> 6;
      int base = ((J * (J + 1) / 2) << 6) + lane * (J + 1);
      for (int I = 0; I <= J; ++I) m[I] = mask[base + I];
    }
    __syncthreads();
  } else {
    // Fallback (V > 704; pathological only): per-thread serial strips with
    // LDS broadcast reads. Correct for any V up to 1024.
    int J = t >> 6;
    float4 bj = sbox[t];
    float areaj = sarea[t];
    for (int I = 0; I <= J; ++I) {
      unsigned long long acc = 0;
      for (int q = 0; q < 64; ++q) {
        int i = (I << 6) + q;
        float4 a = sbox[i];
        float aa = sarea[i];
        float yy1 = fmaxf(a.x, bj.x);
        float xx1 = fmaxf(a.y, bj.y);
        float yy2 = fminf(a.z, bj.z);
        float xx2 = fminf(a.w, bj.w);
        float ih = fmaxf(yy2 - yy1, 0.0f);
        float iw = fmaxf(xx2 - xx1, 0.0f);
        float inter = ih * iw;
        float denom = (aa + areaj) - inter;
        float iou = inter / denom;
        bool pred = aj && (i < t) && (iou > 0.5f);
        if (pred) acc |= (1ull << q);
      }
      m[I] = acc;
    }
    __syncthreads();
  }

  // Bit-parallel Jacobi fixpoint == exact greedy NMS (unique fixpoint;
  // converges in <= suppression-chain-depth iterations).
  for (int it = 0; it < 1024; ++it) {
    bool sup = false;
#pragma unroll
    for (int w = 0; w < 16; ++w) sup = sup || ((m[w] & keepw[w]) != 0ull);
    unsigned long long nb = __ballot(aj && !sup);
    unsigned long long old = keepw[wav];
    __syncthreads();
    if (t == 0) shChanged = 0;
    if (lane == 0) keepw[wav] = nb;
    __syncthreads();
    if (lane == 0 && nb != old) atomicOr(&shChanged, 1);
    __syncthreads();
    if (!shChanged) break;
  }

  // Emit kept records (class rank < 300) + count. Rec format unchanged
  // (verified): score<<32 | (32767-flat)<<10 | n, flat = c*1024 + pos.
  if (t == 0) {
    int tot = 0;
#pragma unroll
    for (int w = 0; w < 16; ++w) tot += (int)__popcll(keepw[w]);
    cnts[bc] = (tot < MAXOUT) ? tot : MAXOUT;
  }
  if (aj && ((keepw[wav] >> lane) & 1ull)) {
    int rank = 0;
    for (int w = 0; w < wav; ++w) rank += (int)__popcll(keepw[w]);
    rank += (int)__popcll(keepw[wav] & ((1ull << lane) - 1ull));
    if (rank < MAXOUT) {
      unsigned sbits = (unsigned)(mine >> 32);
      int n = NBOX - 1 - (int)(mine & (NBOX - 1));
      int flat = c * NBOX + t;
      recs[bc * MAXOUT + rank] = (((unsigned long long)sbits) << 32)
          | ((unsigned)(NCLS * NBOX - 1 - flat) << 10) | (unsigned)n;
    }
  }
}

// One 1024-thread block per batch. Exact top-300 via 256-bucket score
// histogram + suffix scan + exact rank inside the boundary bucket (keys are
// unique). Then LDS atomicMax dedup by box id and ballot-based slot scan.
// (Unchanged from round 3 — verified absmax 0.0.)
__global__ __launch_bounds__(1024) void topk_out(
    const float* __restrict__ boxes,
    const unsigned long long* __restrict__ recs,
    const int* __restrict__ cnts,
    float* __restrict__ out) {
  const int b = blockIdx.x;
  const int tid = threadIdx.x;
  const int lane = tid & 63, wav = tid >> 6;

  __shared__ int hist[256];
  __shared__ int suf[257];
  __shared__ unsigned long long maxKey[NBOX];
  __shared__ unsigned long long blist[1024];
  __shared__ int bcnt;
  __shared__ unsigned long long shT;
  __shared__ int shBstar;
  __shared__ int wcnt[16], woff[16];
  __shared__ int shPresTot;

  const int CAND = NCLS * MAXOUT;
  unsigned long long cand[10];
#pragma unroll
  for (int q = 0; q < 10; ++q) {
    int j = tid + (q << 10);
    unsigned long long v = 0;
    if (j < CAND) {
      int c = j / MAXOUT;
      int r = j - c * MAXOUT;
      if (r < cnts[b * NCLS + c])
        v = recs[(size_t)(b * NCLS + c) * MAXOUT + r];
    }
    cand[q] = v;
  }
  maxKey[tid] = 0;
  if (tid < 256) hist[tid] = 0;
  if (tid == 0) { bcnt = 0; shT = 0; shBstar = -1; }
  __syncthreads();

  // Histogram on score-bit buckets; score in (0.5,1) => bits in
  // (0x3F000000, 0x3F800000) => bucket = (bits - 0x3F000000) >> 15 in [0,255].
#pragma unroll
  for (int q = 0; q < 10; ++q) {
    unsigned long long v = cand[q];
    if (v != 0ull) {
      int bk = (int)(((unsigned)(v >> 32) - 0x3F000000u) >> 15);
      atomicAdd(&hist[bk], 1);
    }
  }
  __syncthreads();

  // Wave 0: suffix sums over the 256 buckets.
  if (wav == 0) {
    int h[4];
#pragma unroll
    for (int g = 0; g < 4; ++g) h[g] = hist[g * 64 + lane];
#pragma unroll
    for (int g = 0; g < 4; ++g) {
      int v = h[g];
#pragma unroll
      for (int off = 1; off < 64; off <<= 1) {
        int u = __shfl_down(v, off);
        if (lane + off < 64) v += u;
      }
      h[g] = v;                       // suffix within group
    }
    int sum1 = __shfl(h[1], 0);
    int sum2 = __shfl(h[2], 0);
    int sum3 = __shfl(h[3], 0);
    suf[0 * 64 + lane] = h[0] + sum1 + sum2 + sum3;
    suf[1 * 64 + lane] = h[1] + sum2 + sum3;
    suf[2 * 64 + lane] = h[2] + sum3;
    suf[3 * 64 + lane] = h[3];
    if (lane == 0) suf[256] = 0;
  }
  __syncthreads();

  // Boundary bucket B*: suf[B*] >= 300 > suf[B*+1]. (-1 if total < 300.)
  if (tid < 256) {
    if (suf[tid] >= MAXOUT && suf[tid + 1] < MAXOUT) shBstar = tid;
  }
  __syncthreads();
  const int Bstar = shBstar;

  if (Bstar >= 0) {   // block-uniform branch
#pragma unroll
    for (int q = 0; q < 10; ++q) {
      unsigned long long v = cand[q];
      if (v != 0ull) {
        int bk = (int)(((unsigned)(v >> 32) - 0x3F000000u) >> 15);
        if (bk == Bstar) { int idx = atomicAdd(&bcnt, 1); blist[idx] = v; }
      }
    }
    __syncthreads();
    int M = bcnt;
    int need = MAXOUT - suf[Bstar + 1];
    if (tid < M) {
      unsigned long long mine = blist[tid];
      int r = 0;
      for (int i = 0; i < M; ++i) r += (blist[i] > mine) ? 1 : 0;
      if (r == need - 1) shT = mine;   // the 300th-largest key overall
    }
    __syncthreads();
  }
  const unsigned long long T = shT;   // 0 => select all nonzero

  // Dedup by original box id: max key == earliest top-300 occurrence.
#pragma unroll
  for (int q = 0; q < 10; ++q) {
    unsigned long long v = cand[q];
    if (v != 0ull && v >= T) {
      int n = (int)(v & (NBOX - 1));
      atomicMax(&maxKey[n], v);
    }
  }
  __syncthreads();

  // Present flags -> output slot via ballot scan (box ids ascending).
  bool pres = (maxKey[tid] != 0ull);
  unsigned long long wm = __ballot(pres);
  if (lane == 0) wcnt[wav] = (int)__popcll(wm);
  __syncthreads();
  if (tid < 16) {
    int v = wcnt[tid];
    int inc = v;
#pragma unroll
    for (int off = 1; off < 16; off <<= 1) {
      int u = __shfl_up(inc, off);
      if (lane >= off) inc += u;
    }
    woff[tid] = inc - v;
    if (tid == 15) shPresTot = inc;
  }
  __syncthreads();
  const int total = shPresTot;

  float* ob = out + (size_t)b * MAXOUT * 4;
  float* os = out + (size_t)NBATCH * MAXOUT * 4 + (size_t)b * MAXOUT;
  float* oc = out + (size_t)NBATCH * MAXOUT * 5 + (size_t)b * MAXOUT;

  if (pres) {
    int slot = woff[wav] + (int)__popcll(wm & ((1ull << lane) - 1ull));
    unsigned long long v = maxKey[tid];
    float score = __uint_as_float((unsigned)(v >> 32));
    int flat = NCLS * NBOX - 1 - (int)((v >> 10) & (unsigned)(NCLS * NBOX - 1));
    int cls = flat >> 10;
    float4 bx = ((const float4*)boxes)[(size_t)b * NBOX + tid];
    ob[slot * 4 + 0] = bx.x;
    ob[slot * 4 + 1] = bx.y;
    ob[slot * 4 + 2] = bx.z;
    ob[slot * 4 + 3] = bx.w;
    os[slot] = score;
    oc[slot] = (float)cls;
  }
  if (tid >= total && tid < MAXOUT) {
    ob[tid * 4 + 0] = 0.0f; ob[tid * 4 + 1] = 0.0f;
    ob[tid * 4 + 2] = 0.0f; ob[tid * 4 + 3] = 0.0f;
    os[tid] = 0.0f;
    oc[tid] = 0.0f;
  }
}

extern "C" void kernel_launch(void* const* d_in, const int* in_sizes, int n_in,
                              void* d_out, int out_size, void* d_ws, size_t ws_size,
                              hipStream_t stream) {
  const float* boxes  = (const float*)d_in[0];   // [8,1024,4] f32
  const float* scores = (const float*)d_in[1];   // [8,1024,32] f32
  float* out = (float*)d_out;                    // boxes ‖ scores ‖ classes (f32)

  unsigned long long* recs = (unsigned long long*)d_ws;  // 256*300 u64
  int* cnts = (int*)((char*)d_ws + (size_t)NBATCH * NCLS * MAXOUT * sizeof(unsigned long long));

  nms_per_class<<<NBATCH * NCLS, 1024, 0, stream>>>(boxes, scores, recs, cnts);
  topk_out<<<NBATCH, 1024, 0, stream>>>(boxes, recs, cnts, out);
}

// Round 5
// 102.970 us; speedup vs baseline: 5.2296x; 1.2185x over previous
//
#include <hip/hip_runtime.h>

// Match numpy f32 semantics exactly: no FMA contraction anywhere in this file.
#pragma clang fp contract(off)

#define NBOX   1024
#define NCLS   32
#define NBATCH 8
#define MAXOUT 300
#define SMAX   11   // fast path handles V <= 704 (Binom(1024,.5): mean 512, sd 16)

// Exact predicate replacement for the reference's  fdiv(inter,denom) > 0.5f :
//   RN(inter/denom) > 0.5  <=>  inter/denom > 0.5*(1+2^-24)   (RN monotone;
//   exact-midpoint quotients are unreachable for f32 operands: a/b = 0.5*(1+2^-24)
//   requires a 25-bit significand factor). RHS product is EXACT in double
//   (24-bit b x 25-bit constant <= 49 bits < 53). Verified-equivalent semantics.
#define MTHR 0x1.000001p-1   // 0.5*(1+2^-24), exactly representable

// 64-bit shfl_xor built from two 32-bit shfls (deterministic, wave64).
__device__ __forceinline__ unsigned long long shflx64(unsigned long long v, int m) {
  unsigned lo = (unsigned)__shfl_xor((int)(unsigned)v, m, 64);
  unsigned hi = (unsigned)__shfl_xor((int)(unsigned)(v >> 32), m, 64);
  return ((unsigned long long)hi << 32) | lo;
}

// Bitonic compare-exchange in registers; final order descending. Keys unique.
__device__ __forceinline__ unsigned long long cexch(
    unsigned long long mine, int jj, int kk, int t) {
  unsigned long long other = shflx64(mine, jj);
  bool iLow = ((t & jj) == 0);
  bool desc = ((t & kk) == 0);
  bool wantMax = (iLow == desc);
  bool otherBigger = (other > mine);
  return (wantMax == otherBigger) ? other : mine;
}

// One 1024-thread block per (batch,class). Thread t owns sorted position t.
__global__ __launch_bounds__(1024) void nms_per_class(
    const float* __restrict__ boxes, const float* __restrict__ scores,
    unsigned long long* __restrict__ recs) {
#pragma clang fp contract(off)
  const int bc = blockIdx.x;
  const int b = bc >> 5;
  const int c = bc & (NCLS - 1);
  const int t = threadIdx.x;
  const int lane = t & 63, wav = t >> 6;

  __shared__ unsigned long long key[NBOX];
  __shared__ float4 sbox[NBOX];
  __shared__ float sarea[NBOX];
  __shared__ unsigned long long mask[64 * 68];   // triangular-packed + pad
  __shared__ unsigned long long kb[2][16];       // double-buffered keep
  __shared__ int chg[64];                        // rotating changed-flags
  __shared__ int shV;

  // Key: score_bits<<32 | (1023-n); invalid => high32==0. Descending order
  // == score desc, ties by original index asc (stable argsort semantics).
  const float* sp = scores + (size_t)b * NBOX * NCLS + c;
  float s = sp[(size_t)t * NCLS];
  bool valid = (s > 0.5f);
  unsigned long long mine = valid
      ? ((((unsigned long long)__float_as_uint(s)) << 32) | (unsigned)(NBOX - 1 - t))
      : (unsigned long long)(unsigned)(NBOX - 1 - t);
  if (t == 0) shV = 0;
  if (t < 64) chg[t] = 0;
  __syncthreads();
  unsigned long long vb = __ballot(valid);
  if (lane == 0) atomicAdd(&shV, (int)__popcll(vb));

  // Bitonic sort, descending. jj<=32 stages in registers (barrier-free);
  // only jj>=64 stages touch LDS (10 LDS stages total).
  for (int kk = 2; kk <= 64; kk <<= 1)
    for (int jj = kk >> 1; jj > 0; jj >>= 1)
      mine = cexch(mine, jj, kk, t);
  key[t] = mine;
  __syncthreads();
  for (int kk = 128; kk <= 1024; kk <<= 1) {
    for (int jj = kk >> 1; jj >= 64; jj >>= 1) {
      if (t < 512) {
        int i = ((t & ~(jj - 1)) << 1) | (t & (jj - 1));
        int ixj = i | jj;
        unsigned long long a = key[i], bb = key[ixj];
        if (((i & kk) == 0) ? (a < bb) : (a > bb)) { key[i] = bb; key[ixj] = a; }
      }
      __syncthreads();
    }
    mine = key[t];
    for (int jj = 32; jj > 0; jj >>= 1) mine = cexch(mine, jj, kk, t);
    key[t] = mine;
    __syncthreads();
  }

  // Gather boxes in sorted order; precompute areas (same expression as ref).
  int n0 = NBOX - 1 - (int)(mine & (NBOX - 1));
  const float4* gb = (const float4*)boxes + (size_t)b * NBOX;
  float4 bx4 = gb[n0];
  sbox[t] = bx4;
  sarea[t] = (bx4.z - bx4.x) * (bx4.w - bx4.y);
  __syncthreads();
  const int V = shV;
  const int S = (V + 63) >> 6;
  const bool aj = (t < V);

  // keep init = valid prefix (buffer 0).
  if (t < 16) {
    int base = t * 64;
    unsigned long long m0;
    if (V >= base + 64) m0 = ~0ull;
    else if (V <= base) m0 = 0ull;
    else m0 = (1ull << (V - base)) - 1ull;
    kb[0][t] = m0;
  }

  unsigned long long m[16];
#pragma unroll
  for (int w = 0; w < 16; ++w) m[w] = 0;

  if (S <= SMAX) {
    // Strip-pair worklist: unit (J,I), I<=J, round-robin over 16 waves.
    // Suppressor boxes broadcast via wave-uniform LDS reads (compile-time
    // offsets, conflict-free). Inner loop = pure IoU math, division-free.
    const int T = S * (S + 1) / 2;
    for (int k = wav; k < T; k += 16) {
      int J = 0;
      while ((J + 1) * (J + 2) / 2 <= k) ++J;   // wave-uniform, <=11 iters
      int I = k - J * (J + 1) / 2;
      const int j = (J << 6) + lane;
      const float4 bj = sbox[j];
      const float areaj = sarea[j];
      const float4* bi = &sbox[I << 6];
      const float* ai = &sarea[I << 6];
      unsigned long long acc = 0;
#pragma unroll
      for (int q = 0; q < 64; ++q) {
        float4 a = bi[q];      // ds_read_b128, uniform addr -> broadcast
        float aa = ai[q];      // ds_read_b32,  uniform addr -> broadcast
        float yy1 = fmaxf(a.x, bj.x);
        float xx1 = fmaxf(a.y, bj.y);
        float yy2 = fminf(a.z, bj.z);
        float xx2 = fminf(a.w, bj.w);
        float ih = fmaxf(yy2 - yy1, 0.0f);
        float iw = fmaxf(xx2 - xx1, 0.0f);
        float inter = ih * iw;
        float denom = (aa + areaj) - inter;
        if ((double)inter > MTHR * (double)denom) acc |= (1ull << q);
      }
      if (I == J) acc &= (1ull << lane) - 1ull;   // enforce i<j on diagonal
      int vrem = V - (I << 6);                    // tail strip: mask i>=V
      if (vrem < 64) acc &= (1ull << vrem) - 1ull;
      mask[((J * (J + 1) / 2) << 6) + lane * (J + 1) + I] = acc;
    }
    __syncthreads();
    if (t < (S << 6)) {                 // wave-uniform branch (J per wave)
      const int J = t >> 6;
      const int rb = ((J * (J + 1) / 2) << 6) + lane * (J + 1);
#pragma unroll
      for (int I = 0; I < 16; ++I)      // static index: m[] stays in VGPRs
        if (I <= J) m[I] = mask[rb + I];
    }
    __syncthreads();
  } else {
    // Fallback (V > 704; statistically unreachable): per-thread strips.
    const int J = t >> 6;
    const float4 bj = sbox[t];
    const float areaj = sarea[t];
#pragma unroll
    for (int I = 0; I < 16; ++I) {
      unsigned long long acc = 0;
      if (I <= J && (I << 6) < V) {
        for (int q = 0; q < 64; ++q) {
          int i = (I << 6) + q;
          float4 a = sbox[i];
          float aa = sarea[i];
          float yy1 = fmaxf(a.x, bj.x);
          float xx1 = fmaxf(a.y, bj.y);
          float yy2 = fminf(a.z, bj.z);
          float xx2 = fminf(a.w, bj.w);
          float ih = fmaxf(yy2 - yy1, 0.0f);
          float iw = fmaxf(xx2 - xx1, 0.0f);
          float inter = ih * iw;
          float denom = (aa + areaj) - inter;
          bool pred = (i < t) && (i < V) &&
                      ((double)inter > MTHR * (double)denom);
          if (pred) acc |= (1ull << q);
        }
      }
      m[I] = acc;
    }
    __syncthreads();
  }

  // Bit-parallel Jacobi fixpoint == exact greedy NMS (unique fixpoint;
  // converges in <= chain-depth+1 iterations). ONE barrier per iteration:
  // double-buffered keep + rotating changed-flag slots (zeroed 32 ahead).
  int cur = 0;
  for (int it = 0; it < 1100; ++it) {
    bool sup = false;
#pragma unroll
    for (int w = 0; w < 16; ++w) sup = sup || ((m[w] & kb[cur][w]) != 0ull);
    unsigned long long nb = __ballot(aj && !sup);
    if (lane == 0) {
      kb[cur ^ 1][wav] = nb;
      if (nb != kb[cur][wav]) atomicOr(&chg[it & 63], 1);
    }
    if (t == 0) chg[(it + 32) & 63] = 0;
    __syncthreads();
    if (chg[it & 63] == 0) break;       // converged: kb[cur^1]==kb[cur]
    cur ^= 1;
  }

  // Emit kept records (class rank < 300), zero-fill the tail so the topk
  // kernel needs no per-class counts. Rec: score<<32 | (32767-flat)<<10 | n.
  int tot = 0;
#pragma unroll
  for (int w = 0; w < 16; ++w) tot += (int)__popcll(kb[cur][w]);
  const int rbase = bc * MAXOUT;
  if (aj && ((kb[cur][wav] >> lane) & 1ull)) {
    int rank = 0;
#pragma unroll
    for (int w = 0; w < 16; ++w)
      if (w < wav) rank += (int)__popcll(kb[cur][w]);
    rank += (int)__popcll(kb[cur][wav] & ((1ull << lane) - 1ull));
    if (rank < MAXOUT) {
      unsigned sbits = (unsigned)(mine >> 32);
      int n = NBOX - 1 - (int)(mine & (NBOX - 1));
      int flat = c * NBOX + t;
      recs[rbase + rank] = (((unsigned long long)sbits) << 32)
          | ((unsigned)(NCLS * NBOX - 1 - flat) << 10) | (unsigned)n;
    }
  }
  if (t < MAXOUT && t >= tot) recs[rbase + t] = 0ull;
}

// One 1024-thread block per batch. Exact top-300 via 256-bucket score
// histogram + suffix scan + exact rank inside the boundary bucket (keys are
// unique). Then LDS atomicMax dedup by box id and ballot-based slot scan.
__global__ __launch_bounds__(1024) void topk_out(
    const float* __restrict__ boxes,
    const unsigned long long* __restrict__ recs,
    float* __restrict__ out) {
  const int b = blockIdx.x;
  const int tid = threadIdx.x;
  const int lane = tid & 63, wav = tid >> 6;

  __shared__ int hist[256];
  __shared__ int suf[257];
  __shared__ unsigned long long maxKey[NBOX];
  __shared__ unsigned long long blist[1024];
  __shared__ int bcnt;
  __shared__ unsigned long long shT;
  __shared__ int shBstar;
  __shared__ int wcnt[16], woff[16];
  __shared__ int shPresTot;

  const int CAND = NCLS * MAXOUT;
  const unsigned long long* rb = recs + (size_t)b * NCLS * MAXOUT;
  unsigned long long cand[10];
#pragma unroll
  for (int q = 0; q < 10; ++q) {
    int j = tid + (q << 10);
    cand[q] = (j < CAND) ? rb[j] : 0ull;   // zero slots are inert
  }
  maxKey[tid] = 0;
  if (tid < 256) hist[tid] = 0;
  if (tid == 0) { bcnt = 0; shT = 0; shBstar = -1; }
  __syncthreads();

  // Histogram on score-bit buckets; score in (0.5,1) => bits in
  // (0x3F000000, 0x3F800000) => bucket = (bits - 0x3F000000) >> 15 in [0,255].
#pragma unroll
  for (int q = 0; q < 10; ++q) {
    unsigned long long v = cand[q];
    if (v != 0ull) {
      int bk = (int)(((unsigned)(v >> 32) - 0x3F000000u) >> 15);
      atomicAdd(&hist[bk], 1);
    }
  }
  __syncthreads();

  // Wave 0: suffix sums over the 256 buckets.
  if (wav == 0) {
    int h[4];
#pragma unroll
    for (int g = 0; g < 4; ++g) h[g] = hist[g * 64 + lane];
#pragma unroll
    for (int g = 0; g < 4; ++g) {
      int v = h[g];
#pragma unroll
      for (int off = 1; off < 64; off <<= 1) {
        int u = __shfl_down(v, off);
        if (lane + off < 64) v += u;
      }
      h[g] = v;                       // suffix within group
    }
    int sum1 = __shfl(h[1], 0);
    int sum2 = __shfl(h[2], 0);
    int sum3 = __shfl(h[3], 0);
    suf[0 * 64 + lane] = h[0] + sum1 + sum2 + sum3;
    suf[1 * 64 + lane] = h[1] + sum2 + sum3;
    suf[2 * 64 + lane] = h[2] + sum3;
    suf[3 * 64 + lane] = h[3];
    if (lane == 0) suf[256] = 0;
  }
  __syncthreads();

  // Boundary bucket B*: suf[B*] >= 300 > suf[B*+1]. (-1 if total < 300.)
  if (tid < 256) {
    if (suf[tid] >= MAXOUT && suf[tid + 1] < MAXOUT) shBstar = tid;
  }
  __syncthreads();
  const int Bstar = shBstar;

  if (Bstar >= 0) {   // block-uniform branch
#pragma unroll
    for (int q = 0; q < 10; ++q) {
      unsigned long long v = cand[q];
      if (v != 0ull) {
        int bk = (int)(((unsigned)(v >> 32) - 0x3F000000u) >> 15);
        if (bk == Bstar) { int idx = atomicAdd(&bcnt, 1); blist[idx] = v; }
      }
    }
    __syncthreads();
    int M = bcnt;
    int need = MAXOUT - suf[Bstar + 1];
    if (tid < M) {
      unsigned long long mine = blist[tid];
      int r = 0;
      for (int i = 0; i < M; ++i) r += (blist[i] > mine) ? 1 : 0;
      if (r == need - 1) shT = mine;   // the 300th-largest key overall
    }
    __syncthreads();
  }
  const unsigned long long T = shT;   // 0 => select all nonzero

  // Dedup by original box id: max key == earliest top-300 occurrence.
#pragma unroll
  for (int q = 0; q < 10; ++q) {
    unsigned long long v = cand[q];
    if (v != 0ull && v >= T) {
      int n = (int)(v & (NBOX - 1));
      atomicMax(&maxKey[n], v);
    }
  }
  __syncthreads();

  // Present flags -> output slot via ballot scan (box ids ascending).
  bool pres = (maxKey[tid] != 0ull);
  unsigned long long wm = __ballot(pres);
  if (lane == 0) wcnt[wav] = (int)__popcll(wm);
  __syncthreads();
  if (tid < 16) {
    int v = wcnt[tid];
    int inc = v;
#pragma unroll
    for (int off = 1; off < 16; off <<= 1) {
      int u = __shfl_up(inc, off);
      if (lane >= off) inc += u;
    }
    woff[tid] = inc - v;
    if (tid == 15) shPresTot = inc;
  }
  __syncthreads();
  const int total = shPresTot;

  float* ob = out + (size_t)b * MAXOUT * 4;
  float* os = out + (size_t)NBATCH * MAXOUT * 4 + (size_t)b * MAXOUT;
  float* oc = out + (size_t)NBATCH * MAXOUT * 5 + (size_t)b * MAXOUT;

  if (pres) {
    int slot = woff[wav] + (int)__popcll(wm & ((1ull << lane) - 1ull));
    unsigned long long v = maxKey[tid];
    float score = __uint_as_float((unsigned)(v >> 32));
    int flat = NCLS * NBOX - 1 - (int)((v >> 10) & (unsigned)(NCLS * NBOX - 1));
    int cls = flat >> 10;
    float4 bx = ((const float4*)boxes)[(size_t)b * NBOX + tid];
    ob[slot * 4 + 0] = bx.x;
    ob[slot * 4 + 1] = bx.y;
    ob[slot * 4 + 2] = bx.z;
    ob[slot * 4 + 3] = bx.w;
    os[slot] = score;
    oc[slot] = (float)cls;
  }
  if (tid >= total && tid < MAXOUT) {
    ob[tid * 4 + 0] = 0.0f; ob[tid * 4 + 1] = 0.0f;
    ob[tid * 4 + 2] = 0.0f; ob[tid * 4 + 3] = 0.0f;
    os[tid] = 0.0f;
    oc[tid] = 0.0f;
  }
}

extern "C" void kernel_launch(void* const* d_in, const int* in_sizes, int n_in,
                              void* d_out, int out_size, void* d_ws, size_t ws_size,
                              hipStream_t stream) {
  const float* boxes  = (const float*)d_in[0];   // [8,1024,4] f32
  const float* scores = (const float*)d_in[1];   // [8,1024,32] f32
  float* out = (float*)d_out;                    // boxes ‖ scores ‖ classes (f32)

  unsigned long long* recs = (unsigned long long*)d_ws;  // 256*300 u64, fully rewritten per launch

  nms_per_class<<<NBATCH * NCLS, 1024, 0, stream>>>(boxes, scores, recs);
  topk_out<<<NBATCH, 1024, 0, stream>>>(boxes, recs, out);
}

// Round 6
// 102.453 us; speedup vs baseline: 5.2560x; 1.0050x over previous
//
#include <hip/hip_runtime.h>

// Match numpy f32 semantics exactly: no FMA contraction anywhere in this file.
#pragma clang fp contract(off)

#define NBOX   1024
#define NCLS   32
#define NBATCH 8
#define MAXOUT 300
#define SMAX   11   // fast path handles V <= 704 (Binom(1024,.5): mean 512, sd 16)

// Exact all-f32 replacement for the reference's  RN(inter/denom) > 0.5f :
//   RN(I/D) > 0.5  <=>  I/D > 0.5*(1+2^-24)      (RN monotone; midpoint
//   quotients unreachable for f32 operands)      <=>  2I - D > D*2^-24.
//   Computed:  lhs = RN(2I - D): 2I exact; I_c <= D_c always (RN-monotone
//   bound I <= min(A,B) and D >= I), so for I/D in [1/4,1] Sterbenz gives
//   lhs exact; for I/D < 1/4 sign is preserved (predicate false both ways).
//   rhs = RN(D*2^-24) is an exact exponent shift (D >= ~1 here).
//   => (lhs > rhs) is bit-exactly the reference predicate.
#define IOU_SUP(ab, aa, bj, arj, act, acc) do {               \
    float yy1 = fmaxf((ab).x, (bj).x);                        \
    float xx1 = fmaxf((ab).y, (bj).y);                        \
    float yy2 = fminf((ab).z, (bj).z);                        \
    float xx2 = fminf((ab).w, (bj).w);                        \
    float ih = fmaxf(yy2 - yy1, 0.0f);                        \
    float iw = fmaxf(xx2 - xx1, 0.0f);                        \
    float inter = ih * iw;                                    \
    float denom = ((aa) + (arj)) - inter;                     \
    float lhs = (inter + inter) - denom;                      \
    float rhs = denom * 5.9604644775390625e-08f;              \
    if ((act) && (lhs > rhs)) (acc) |= bit;                   \
  } while (0)

// 64-bit shfl_xor built from two 32-bit shfls (deterministic, wave64).
__device__ __forceinline__ unsigned long long shflx64(unsigned long long v, int m) {
  unsigned lo = (unsigned)__shfl_xor((int)(unsigned)v, m, 64);
  unsigned hi = (unsigned)__shfl_xor((int)(unsigned)(v >> 32), m, 64);
  return ((unsigned long long)hi << 32) | lo;
}

// Bitonic compare-exchange in registers; final order descending. Keys unique.
__device__ __forceinline__ unsigned long long cexch(
    unsigned long long mine, int jj, int kk, int t) {
  unsigned long long other = shflx64(mine, jj);
  bool iLow = ((t & jj) == 0);
  bool desc = ((t & kk) == 0);
  bool wantMax = (iLow == desc);
  bool otherBigger = (other > mine);
  return (wantMax == otherBigger) ? other : mine;
}

// One 1024-thread block per (batch,class). Thread t owns sorted position t.
__global__ __launch_bounds__(1024) void nms_per_class(
    const float* __restrict__ boxes, const float* __restrict__ scores,
    unsigned long long* __restrict__ recs) {
#pragma clang fp contract(off)
  const int bc = blockIdx.x;
  const int b = bc >> 5;
  const int c = bc & (NCLS - 1);
  const int t = threadIdx.x;
  const int lane = t & 63, wav = t >> 6;

  __shared__ unsigned long long key[NBOX];
  __shared__ float4 sbox[NBOX];
  __shared__ float sarea[NBOX];
  __shared__ unsigned long long mask[64 * 68];   // triangular-packed + pad
  __shared__ unsigned long long kb[16];          // final keep words
  __shared__ int shV;

  // Key: score_bits<<32 | (1023-n); invalid => high32==0. Descending order
  // == score desc, ties by original index asc (stable argsort semantics).
  const float* sp = scores + (size_t)b * NBOX * NCLS + c;
  float s = sp[(size_t)t * NCLS];
  bool valid = (s > 0.5f);
  unsigned long long mine = valid
      ? ((((unsigned long long)__float_as_uint(s)) << 32) | (unsigned)(NBOX - 1 - t))
      : (unsigned long long)(unsigned)(NBOX - 1 - t);
  if (t == 0) shV = 0;
  if (t < 16) kb[t] = 0ull;
  __syncthreads();
  unsigned long long vb = __ballot(valid);
  if (lane == 0) atomicAdd(&shV, (int)__popcll(vb));

  // Bitonic sort, descending. jj<=32 stages in registers (barrier-free);
  // only jj>=64 stages touch LDS (10 LDS stages total).
  for (int kk = 2; kk <= 64; kk <<= 1)
    for (int jj = kk >> 1; jj > 0; jj >>= 1)
      mine = cexch(mine, jj, kk, t);
  key[t] = mine;
  __syncthreads();
  for (int kk = 128; kk <= 1024; kk <<= 1) {
    for (int jj = kk >> 1; jj >= 64; jj >>= 1) {
      if (t < 512) {
        int i = ((t & ~(jj - 1)) << 1) | (t & (jj - 1));
        int ixj = i | jj;
        unsigned long long a = key[i], bb = key[ixj];
        if (((i & kk) == 0) ? (a < bb) : (a > bb)) { key[i] = bb; key[ixj] = a; }
      }
      __syncthreads();
    }
    mine = key[t];
    for (int jj = 32; jj > 0; jj >>= 1) mine = cexch(mine, jj, kk, t);
    key[t] = mine;
    __syncthreads();
  }

  // Gather boxes in sorted order; precompute areas (same expression as ref).
  int n0 = NBOX - 1 - (int)(mine & (NBOX - 1));
  const float4* gb = (const float4*)boxes + (size_t)b * NBOX;
  float4 bx4 = gb[n0];
  sbox[t] = bx4;
  sarea[t] = (bx4.z - bx4.x) * (bx4.w - bx4.y);
  __syncthreads();
  const int V = shV;
  const int S = (V + 63) >> 6;
  const bool aj = (t < V);

  // Per-thread suppressor masks: mext[I] = suppressors in word I (< my word),
  // mself = suppressors within my own word (bits strictly below my lane).
  unsigned long long mext[15];
  unsigned long long mself = 0ull;
#pragma unroll
  for (int w = 0; w < 15; ++w) mext[w] = 0ull;

  if (S <= SMAX) {
    // Chunk = (I-strip, up to 3 consecutive J-strips). The broadcast reads
    // of strip I (ds_read_b128 + b32, wave-uniform -> conflict-free) are
    // amortized over 3 IoU evaluations: LDS-pipe load drops ~3x vs 1 strip.
    int NC = 0;
    for (int I2 = 0; I2 < S; ++I2) NC += (S - I2 + 2) / 3;
    for (int k = wav; k < NC; k += 16) {
      int I = 0, rem = k;
      for (;;) { int cI = (S - I + 2) / 3; if (rem < cI) break; rem -= cI; ++I; }
      const int J0 = I + 3 * rem;
      const bool h1 = (J0 + 1 < S), h2 = (J0 + 2 < S);
      const int j0 = (J0 << 6) + lane;
      const int j1 = h1 ? j0 + 64 : j0;
      const int j2 = h2 ? j0 + 128 : j0;
      const float4 b0 = sbox[j0]; const float ar0 = sarea[j0];
      const float4 b1 = sbox[j1]; const float ar1 = sarea[j1];
      const float4 b2 = sbox[j2]; const float ar2 = sarea[j2];
      const bool act0 = (j0 < V);
      const bool act1 = h1 && (j0 + 64 < V);
      const bool act2 = h2 && (j0 + 128 < V);
      const float4* bi = &sbox[I << 6];
      const float* ai = &sarea[I << 6];
      unsigned long long a0 = 0, a1 = 0, a2 = 0;
      unsigned long long bit = 1ull;
#pragma unroll 8
      for (int q = 0; q < 64; ++q) {
        float4 ab = bi[q];      // ds_read_b128, uniform addr -> broadcast
        float aa = ai[q];       // ds_read_b32,  uniform addr -> broadcast
        IOU_SUP(ab, aa, b0, ar0, act0, a0);
        IOU_SUP(ab, aa, b1, ar1, act1, a1);
        IOU_SUP(ab, aa, b2, ar2, act2, a2);
        bit <<= 1;
      }
      if (rem == 0) a0 &= (1ull << lane) - 1ull;  // diagonal: enforce i<j
      const int vrem = V - (I << 6);              // tail strip: mask i>=V
      if (vrem < 64) {
        unsigned long long tm = (1ull << vrem) - 1ull;
        a0 &= tm; a1 &= tm; a2 &= tm;
      }
      mask[(((J0 * (J0 + 1) / 2) << 6) + lane * (J0 + 1)) + I] = a0;
      if (h1) mask[((((J0 + 1) * (J0 + 2) / 2) << 6) + lane * (J0 + 2)) + I] = a1;
      if (h2) mask[((((J0 + 2) * (J0 + 3) / 2) << 6) + lane * (J0 + 3)) + I] = a2;
    }
    __syncthreads();
    if (t < (S << 6)) {                 // wave-uniform branch (J per wave)
      const int J = wav;
      const int rbs = ((J * (J + 1) / 2) << 6) + lane * (J + 1);
#pragma unroll
      for (int I = 0; I < 15; ++I)      // static index: mext stays in VGPRs
        if (I < J) mext[I] = mask[rbs + I];
      mself = mask[rbs + J];            // diagonal word (bits < lane only)
    }
  } else {
    // Fallback (V > 704; statistically unreachable): per-thread strips.
    const int J = wav;
    const float4 bj = sbox[t];
    const float arj = sarea[t];
#pragma unroll
    for (int I = 0; I < 16; ++I) {
      if (I <= J && (I << 6) < V) {
        unsigned long long acc = 0, bit = 1ull;
        for (int q = 0; q < 64; ++q) {
          int i = (I << 6) + q;
          float4 ab = sbox[i];
          float aa = sarea[i];
          bool act = aj && (i < t) && (i < V);
          IOU_SUP(ab, aa, bj, arj, act, acc);
          bit <<= 1;
        }
        if (I == J) mself = acc;
        else mext[I] = acc;
      }
    }
  }
  __syncthreads();

  // Word-sequential Gauss-Seidel resolve == exact greedy NMS. Wave w
  // resolves keep-word w alone (earlier words are FINAL in kb[]): external
  // suppression from regs, then an intra-wave ballot fixpoint (unique
  // fixpoint by DAG induction; stop condition nb==cur is exact).
  const int NW = S;
  for (int w = 0; w < NW; ++w) {
    if (wav == w) {
      bool supExt = false;
#pragma unroll
      for (int i = 0; i < 15; ++i)
        if (i < w) supExt = supExt || ((mext[i] & kb[i]) != 0ull);
      bool alive = aj && !supExt;
      unsigned long long cur = __ballot(alive);
      for (;;) {
        unsigned long long nb = __ballot(alive && ((mself & cur) == 0ull));
        if (nb == cur) break;
        cur = nb;
      }
      if (lane == 0) kb[w] = cur;
    }
    __syncthreads();
  }

  // Emit kept records (class rank < 300), zero-fill tail so topk needs no
  // counts. Rec: score<<32 | (32767-flat)<<10 | n, flat = c*1024 + pos.
  unsigned long long kbr[16];
#pragma unroll
  for (int w = 0; w < 16; ++w) kbr[w] = kb[w];
  int tot = 0;
#pragma unroll
  for (int w = 0; w < 16; ++w) tot += (int)__popcll(kbr[w]);
  const int rbase = bc * MAXOUT;
  unsigned long long kw = kbr[0];
#pragma unroll
  for (int w = 1; w < 16; ++w) if (w == wav) kw = kbr[w];
  if (aj && ((kw >> lane) & 1ull)) {
    int rank = 0;
#pragma unroll
    for (int w = 0; w < 16; ++w)
      if (w < wav) rank += (int)__popcll(kbr[w]);
    rank += (int)__popcll(kw & ((1ull << lane) - 1ull));
    if (rank < MAXOUT) {
      unsigned sbits = (unsigned)(mine >> 32);
      int n = NBOX - 1 - (int)(mine & (NBOX - 1));
      int flat = c * NBOX + t;
      recs[rbase + rank] = (((unsigned long long)sbits) << 32)
          | ((unsigned)(NCLS * NBOX - 1 - flat) << 10) | (unsigned)n;
    }
  }
  if (t < MAXOUT && t >= tot) recs[rbase + t] = 0ull;
}

// One 1024-thread block per batch. Exact top-300 via 256-bucket score
// histogram (wave-private copies to cut LDS-atomic contention) + suffix
// scan + exact rank inside the boundary bucket (keys unique). Then LDS
// atomicMax dedup by box id and ballot-based slot scan.
__global__ __launch_bounds__(1024) void topk_out(
    const float* __restrict__ boxes,
    const unsigned long long* __restrict__ recs,
    float* __restrict__ out) {
  const int b = blockIdx.x;
  const int tid = threadIdx.x;
  const int lane = tid & 63, wav = tid >> 6;

  __shared__ int histw[16 * 256];
  __shared__ int hist[256];
  __shared__ int suf[257];
  __shared__ unsigned long long maxKey[NBOX];
  __shared__ unsigned long long blist[1024];
  __shared__ int bcnt;
  __shared__ unsigned long long shT;
  __shared__ int shBstar;
  __shared__ int wcnt[16], woff[16];
  __shared__ int shPresTot;

  const int CAND = NCLS * MAXOUT;
  const unsigned long long* rb = recs + (size_t)b * NCLS * MAXOUT;
  unsigned long long cand[10];
#pragma unroll
  for (int q = 0; q < 10; ++q) {
    int j = tid + (q << 10);
    cand[q] = (j < CAND) ? rb[j] : 0ull;   // zero slots are inert
  }
  maxKey[tid] = 0;
#pragma unroll
  for (int q = 0; q < 4; ++q) histw[tid + (q << 10)] = 0;
  if (tid == 0) { bcnt = 0; shT = 0; shBstar = -1; }
  __syncthreads();

  // Histogram on score-bit buckets; score in (0.5,1) => bits in
  // (0x3F000000, 0x3F800000) => bucket = (bits - 0x3F000000) >> 15 in [0,255].
#pragma unroll
  for (int q = 0; q < 10; ++q) {
    unsigned long long v = cand[q];
    if (v != 0ull) {
      int bk = (int)(((unsigned)(v >> 32) - 0x3F000000u) >> 15);
      atomicAdd(&histw[(wav << 8) + bk], 1);
    }
  }
  __syncthreads();
  if (tid < 256) {
    int ssum = 0;
#pragma unroll
    for (int w = 0; w < 16; ++w) ssum += histw[(w << 8) + tid];
    hist[tid] = ssum;
  }
  __syncthreads();

  // Wave 0: suffix sums over the 256 buckets.
  if (wav == 0) {
    int h[4];
#pragma unroll
    for (int g = 0; g < 4; ++g) h[g] = hist[g * 64 + lane];
#pragma unroll
    for (int g = 0; g < 4; ++g) {
      int v = h[g];
#pragma unroll
      for (int off = 1; off < 64; off <<= 1) {
        int u = __shfl_down(v, off);
        if (lane + off < 64) v += u;
      }
      h[g] = v;                       // suffix within group
    }
    int sum1 = __shfl(h[1], 0);
    int sum2 = __shfl(h[2], 0);
    int sum3 = __shfl(h[3], 0);
    suf[0 * 64 + lane] = h[0] + sum1 + sum2 + sum3;
    suf[1 * 64 + lane] = h[1] + sum2 + sum3;
    suf[2 * 64 + lane] = h[2] + sum3;
    suf[3 * 64 + lane] = h[3];
    if (lane == 0) suf[256] = 0;
  }
  __syncthreads();

  // Boundary bucket B*: suf[B*] >= 300 > suf[B*+1]. (-1 if total < 300.)
  if (tid < 256) {
    if (suf[tid] >= MAXOUT && suf[tid + 1] < MAXOUT) shBstar = tid;
  }
  __syncthreads();
  const int Bstar = shBstar;

  if (Bstar >= 0) {   // block-uniform branch
#pragma unroll
    for (int q = 0; q < 10; ++q) {
      unsigned long long v = cand[q];
      if (v != 0ull) {
        int bk = (int)(((unsigned)(v >> 32) - 0x3F000000u) >> 15);
        if (bk == Bstar) { int idx = atomicAdd(&bcnt, 1); blist[idx] = v; }
      }
    }
    __syncthreads();
    int M = bcnt;
    int need = MAXOUT - suf[Bstar + 1];
    if (tid < M) {
      unsigned long long mine = blist[tid];
      int r = 0;
      for (int i = 0; i < M; ++i) r += (blist[i] > mine) ? 1 : 0;
      if (r == need - 1) shT = mine;   // the 300th-largest key overall
    }
    __syncthreads();
  }
  const unsigned long long T = shT;   // 0 => select all nonzero

  // Dedup by original box id: max key == earliest top-300 occurrence.
#pragma unroll
  for (int q = 0; q < 10; ++q) {
    unsigned long long v = cand[q];
    if (v != 0ull && v >= T) {
      int n = (int)(v & (NBOX - 1));
      atomicMax(&maxKey[n], v);
    }
  }
  __syncthreads();

  // Present flags -> output slot via ballot scan (box ids ascending).
  bool pres = (maxKey[tid] != 0ull);
  unsigned long long wm = __ballot(pres);
  if (lane == 0) wcnt[wav] = (int)__popcll(wm);
  __syncthreads();
  if (tid < 16) {
    int v = wcnt[tid];
    int inc = v;
#pragma unroll
    for (int off = 1; off < 16; off <<= 1) {
      int u = __shfl_up(inc, off);
      if (lane >= off) inc += u;
    }
    woff[tid] = inc - v;
    if (tid == 15) shPresTot = inc;
  }
  __syncthreads();
  const int total = shPresTot;

  float* ob = out + (size_t)b * MAXOUT * 4;
  float* os = out + (size_t)NBATCH * MAXOUT * 4 + (size_t)b * MAXOUT;
  float* oc = out + (size_t)NBATCH * MAXOUT * 5 + (size_t)b * MAXOUT;

  if (pres) {
    int slot = woff[wav] + (int)__popcll(wm & ((1ull << lane) - 1ull));
    unsigned long long v = maxKey[tid];
    float score = __uint_as_float((unsigned)(v >> 32));
    int flat = NCLS * NBOX - 1 - (int)((v >> 10) & (unsigned)(NCLS * NBOX - 1));
    int cls = flat >> 10;
    float4 bx = ((const float4*)boxes)[(size_t)b * NBOX + tid];
    ob[slot * 4 + 0] = bx.x;
    ob[slot * 4 + 1] = bx.y;
    ob[slot * 4 + 2] = bx.z;
    ob[slot * 4 + 3] = bx.w;
    os[slot] = score;
    oc[slot] = (float)cls;
  }
  if (tid >= total && tid < MAXOUT) {
    ob[tid * 4 + 0] = 0.0f; ob[tid * 4 + 1] = 0.0f;
    ob[tid * 4 + 2] = 0.0f; ob[tid * 4 + 3] = 0.0f;
    os[tid] = 0.0f;
    oc[tid] = 0.0f;
  }
}

extern "C" void kernel_launch(void* const* d_in, const int* in_sizes, int n_in,
                              void* d_out, int out_size, void* d_ws, size_t ws_size,
                              hipStream_t stream) {
  const float* boxes  = (const float*)d_in[0];   // [8,1024,4] f32
  const float* scores = (const float*)d_in[1];   // [8,1024,32] f32
  float* out = (float*)d_out;                    // boxes ‖ scores ‖ classes (f32)

  unsigned long long* recs = (unsigned long long*)d_ws;  // 256*300 u64, fully rewritten per launch

  nms_per_class<<<NBATCH * NCLS, 1024, 0, stream>>>(boxes, scores, recs);
  topk_out<<<NBATCH, 1024, 0, stream>>>(boxes, recs, out);
}